// Round 6
// baseline (312.203 us; speedup 1.0000x reference)
//
#include <hip/hip_runtime.h>
#include <hip/hip_bf16.h>
#include <math.h>

#define NN 50000
#define NE 800000
#define SCAN_NB ((NN + 255) / 256)            // 196
#define PROJ_NBLK ((NN + 31) / 32)            // 1563, 32 rows/block
#define ELR_NBLK ((NN + 31) / 32)             // 1563, 32 nodes/block

// ---------------- K_prep: v[hlr][k] = sum_d W[h*32+d][k] * a_{l|r}[h*32+d] ----------------
__global__ __launch_bounds__(256) void k_prep(const float* __restrict__ W,
                                              const float* __restrict__ al,
                                              const float* __restrict__ ar,
                                              float* __restrict__ vlr) {
    int t = threadIdx.x;
    int hlr = t >> 5;            // 0..7
    int k4 = t & 31;             // float4 index within row of 128
    int h = hlr & 3;
    const float* a = (hlr & 4) ? ar : al;
    float4 acc = make_float4(0.f, 0.f, 0.f, 0.f);
    for (int d = 0; d < 32; ++d) {
        float av = a[h * 32 + d];
        float4 wv = *reinterpret_cast<const float4*>(W + (size_t)(h * 32 + d) * 128 + k4 * 4);
        acc.x += av * wv.x; acc.y += av * wv.y;
        acc.z += av * wv.z; acc.w += av * wv.w;
    }
    *reinterpret_cast<float4*>(vlr + hlr * 128 + k4 * 4) = acc;
}

// ---------------- K_elr: elr[n][8] = X[n] . v[hlr], 8 lanes per node ----------------
__global__ __launch_bounds__(256) void k_elr(const float* __restrict__ X,
                                             const float* __restrict__ vlr,
                                             float* __restrict__ elr) {
    __shared__ float vs[8 * 128];
    int t = threadIdx.x;
    for (int i = t; i < 1024; i += 256) vs[i] = vlr[i];
    __syncthreads();
    int lane = t & 63, wave = t >> 6;
    int grp = lane >> 3;          // node within wave's 8
    int j = lane & 7;             // k-chunk of 16
    int node = blockIdx.x * 32 + wave * 8 + grp;
    float a0 = 0.f, a1 = 0.f, a2 = 0.f, a3 = 0.f, a4 = 0.f, a5 = 0.f, a6 = 0.f, a7 = 0.f;
    if (node < NN) {
        const float4* xp = reinterpret_cast<const float4*>(X + (size_t)node * 128 + j * 16);
#pragma unroll
        for (int s = 0; s < 4; ++s) {
            float4 xv = xp[s];
            const float* vb = &vs[j * 16 + s * 4];
            float4 v0 = *reinterpret_cast<const float4*>(vb + 0 * 128);
            float4 v1 = *reinterpret_cast<const float4*>(vb + 1 * 128);
            float4 v2 = *reinterpret_cast<const float4*>(vb + 2 * 128);
            float4 v3 = *reinterpret_cast<const float4*>(vb + 3 * 128);
            float4 v4 = *reinterpret_cast<const float4*>(vb + 4 * 128);
            float4 v5 = *reinterpret_cast<const float4*>(vb + 5 * 128);
            float4 v6 = *reinterpret_cast<const float4*>(vb + 6 * 128);
            float4 v7 = *reinterpret_cast<const float4*>(vb + 7 * 128);
            a0 += xv.x * v0.x + xv.y * v0.y + xv.z * v0.z + xv.w * v0.w;
            a1 += xv.x * v1.x + xv.y * v1.y + xv.z * v1.z + xv.w * v1.w;
            a2 += xv.x * v2.x + xv.y * v2.y + xv.z * v2.z + xv.w * v2.w;
            a3 += xv.x * v3.x + xv.y * v3.y + xv.z * v3.z + xv.w * v3.w;
            a4 += xv.x * v4.x + xv.y * v4.y + xv.z * v4.z + xv.w * v4.w;
            a5 += xv.x * v5.x + xv.y * v5.y + xv.z * v5.z + xv.w * v5.w;
            a6 += xv.x * v6.x + xv.y * v6.y + xv.z * v6.z + xv.w * v6.w;
            a7 += xv.x * v7.x + xv.y * v7.y + xv.z * v7.z + xv.w * v7.w;
        }
    }
#pragma unroll
    for (int off = 1; off <= 4; off <<= 1) {
        a0 += __shfl_xor(a0, off); a1 += __shfl_xor(a1, off);
        a2 += __shfl_xor(a2, off); a3 += __shfl_xor(a3, off);
        a4 += __shfl_xor(a4, off); a5 += __shfl_xor(a5, off);
        a6 += __shfl_xor(a6, off); a7 += __shfl_xor(a7, off);
    }
    float outv = (j == 0) ? a0 : (j == 1) ? a1 : (j == 2) ? a2 : (j == 3) ? a3
               : (j == 4) ? a4 : (j == 5) ? a5 : (j == 6) ? a6 : a7;
    if (node < NN) elr[(size_t)node * 8 + j] = outv;
}

// ---------------- K_proj4: pure GEMM -> bf16 feat; W slice in registers ----------------
__global__ __launch_bounds__(256) void k_proj4(const float* __restrict__ X,
                                               const float* __restrict__ W,
                                               __hip_bfloat16* __restrict__ FB) {
    __shared__ float Xs[32 * 128];   // 16 KiB
    const int t = threadIdx.x;
    const int w = t >> 6, l = t & 63;
    const int c = w * 32 + (l & 31);
    const int kh = (l >> 5) * 64;

    float4 wreg[16];
#pragma unroll
    for (int j = 0; j < 16; ++j)
        wreg[j] = *reinterpret_cast<const float4*>(W + (size_t)c * 128 + kh + j * 4);

    const int r0 = blockIdx.x * 32;
#pragma unroll
    for (int i = 0; i < 4; ++i) {
        int idx = t + i * 256;                 // 1024 float4 slots
        int rr = idx >> 5, c4 = (idx & 31) * 4;
        int r = r0 + rr;
        float4 v = make_float4(0.f, 0.f, 0.f, 0.f);
        if (r < NN) v = *reinterpret_cast<const float4*>(X + (size_t)r * 128 + c4);
        *reinterpret_cast<float4*>(&Xs[rr * 128 + c4]) = v;
    }
    __syncthreads();

#pragma unroll 2
    for (int rr = 0; rr < 32; ++rr) {
        const float4* xp = reinterpret_cast<const float4*>(&Xs[rr * 128 + kh]);
        float a0 = 0.f, a1 = 0.f, a2 = 0.f, a3 = 0.f;
#pragma unroll
        for (int j = 0; j < 16; ++j) {
            float4 x = xp[j];
            a0 += x.x * wreg[j].x; a1 += x.y * wreg[j].y;
            a2 += x.z * wreg[j].z; a3 += x.w * wreg[j].w;
        }
        float tot = (a0 + a1) + (a2 + a3);
        tot += __shfl_xor(tot, 32);
        int row = r0 + rr;
        if (l < 32 && row < NN) FB[(size_t)row * 128 + c] = __float2bfloat16(tot);
    }
}

// ---------------- K2: edge logits in EDGE ORDER (coalesced) + dst histogram ----------------
__global__ void k_logits_hist(const float* __restrict__ FE, const int* __restrict__ src,
                              const int* __restrict__ dst, const float* __restrict__ ae,
                              const float* __restrict__ elr, float4* __restrict__ logits4,
                              int* __restrict__ count) {
    int e = blockIdx.x * 256 + threadIdx.x;
    if (e >= NE) return;
    float fe[16];
#pragma unroll
    for (int i = 0; i < 4; ++i) {
        float4 v = *reinterpret_cast<const float4*>(FE + (size_t)e * 16 + i * 4);
        fe[i * 4 + 0] = v.x; fe[i * 4 + 1] = v.y; fe[i * 4 + 2] = v.z; fe[i * 4 + 3] = v.w;
    }
    int s = src[e], d = dst[e];
    float4 elv = *reinterpret_cast<const float4*>(elr + (size_t)s * 8);
    float4 erv = *reinterpret_cast<const float4*>(elr + (size_t)d * 8 + 4);
    float base[4] = {elv.x + erv.x, elv.y + erv.y, elv.z + erv.z, elv.w + erv.w};
    float o[4];
#pragma unroll
    for (int h = 0; h < 4; ++h) {
        float ee = 0.f;
#pragma unroll
        for (int i = 0; i < 16; ++i) ee += fe[i] * ae[h * 16 + i];
        float v = base[h] + ee;
        o[h] = v > 0.f ? v : 0.2f * v;
    }
    logits4[e] = make_float4(o[0], o[1], o[2], o[3]);
    atomicAdd(&count[d], 1);
}

// ---------------- K3: hierarchical scan ----------------
__global__ __launch_bounds__(256) void k_scan_a(const int* __restrict__ count,
                                                int* __restrict__ pre,
                                                int* __restrict__ bsum) {
    __shared__ int buf[256];
    int t = threadIdx.x;
    int gid = blockIdx.x * 256 + t;
    int v = (gid < NN) ? count[gid] : 0;
    int x = v;
    buf[t] = x;
    __syncthreads();
    for (int off = 1; off < 256; off <<= 1) {
        int add = (t >= off) ? buf[t - off] : 0;
        __syncthreads();
        x += add;
        buf[t] = x;
        __syncthreads();
    }
    if (gid < NN) pre[gid] = x - v;
    if (t == 255) bsum[blockIdx.x] = x;
}

__global__ __launch_bounds__(256) void k_scan_b(const int* __restrict__ bsum,
                                                int* __restrict__ bofs) {
    __shared__ int buf[256];
    int t = threadIdx.x;
    int v = (t < SCAN_NB) ? bsum[t] : 0;
    int x = v;
    buf[t] = x;
    __syncthreads();
    for (int off = 1; off < 256; off <<= 1) {
        int add = (t >= off) ? buf[t - off] : 0;
        __syncthreads();
        x += add;
        buf[t] = x;
        __syncthreads();
    }
    if (t < SCAN_NB) bofs[t] = x - v;
    if (t == 255) bofs[SCAN_NB] = x;
}

__global__ __launch_bounds__(256) void k_scan_c(int* __restrict__ pre,
                                                const int* __restrict__ bofs,
                                                int* __restrict__ cursor) {
    int gid = blockIdx.x * 256 + threadIdx.x;
    if (gid < NN) {
        int val = pre[gid] + bofs[gid >> 8];
        pre[gid] = val;
        cursor[gid] = val;
    }
    if (gid == 0) pre[NN] = bofs[SCAN_NB];
}

// ---------------- K4: fill edge list (CSR by dst), 4B scatter ----------------
__global__ void k_fill(const int* __restrict__ dst, int* __restrict__ cursor,
                       int* __restrict__ edge_list) {
    int e = blockIdx.x * 256 + threadIdx.x;
    if (e >= NE) return;
    int d = dst[e];
    int pos = atomicAdd(&cursor[d], 1);
    edge_list[pos] = e;
}

// ---------------- K5: softmax + aggregation; gather logits/src via edge_list ----------------
__global__ __launch_bounds__(256) void k_aggr5(
    const __hip_bfloat16* __restrict__ FB, const float* __restrict__ lg4,
    const int* __restrict__ srcv, const int* __restrict__ edge_list,
    const int* __restrict__ row_ptr, float* __restrict__ out)
{
    __shared__ float wex[4][64 * 4];     // per-wave exp cache (deg<=64 fast path)
    __shared__ int   sE[4][64];          // per-wave src cache
    int wid = threadIdx.x >> 6, lane = threadIdx.x & 63;
    int node = blockIdx.x * 4 + wid;
    if (node >= NN) return;
    int s0 = row_ptr[node], s1 = row_ptr[node + 1];
    int q = lane & 15, p = lane >> 4;
    float4* o4 = reinterpret_cast<float4*>(out + (size_t)node * 128);
    if (s1 == s0) {
        if (p == 0) {
            o4[2 * q]     = make_float4(0.f, 0.f, 0.f, 0.f);
            o4[2 * q + 1] = make_float4(0.f, 0.f, 0.f, 0.f);
        }
        return;
    }
    const float4* lgf4 = reinterpret_cast<const float4*>(lg4);
    const int deg = s1 - s0;
    const bool small = deg <= 64;

    // pass 1: gather edge id, logits, src (coalesced edge_list; cached random reads)
    bool have = lane < deg;
    int e = have ? edge_list[s0 + lane] : 0;
    int sv = have ? srcv[e] : 0;
    float4 my = have ? lgf4[e] : make_float4(-1e30f, -1e30f, -1e30f, -1e30f);
    float m0 = my.x, m1 = my.y, m2 = my.z, m3 = my.w;
    if (!small) {
        for (int i = s0 + lane + 64; i < s1; i += 64) {
            float4 lg = lgf4[edge_list[i]];
            m0 = fmaxf(m0, lg.x); m1 = fmaxf(m1, lg.y);
            m2 = fmaxf(m2, lg.z); m3 = fmaxf(m3, lg.w);
        }
    }
#pragma unroll
    for (int off = 32; off; off >>= 1) {
        m0 = fmaxf(m0, __shfl_xor(m0, off)); m1 = fmaxf(m1, __shfl_xor(m1, off));
        m2 = fmaxf(m2, __shfl_xor(m2, off)); m3 = fmaxf(m3, __shfl_xor(m3, off));
    }
    float t0 = have ? __expf(my.x - m0) : 0.f;
    float t1 = have ? __expf(my.y - m1) : 0.f;
    float t2 = have ? __expf(my.z - m2) : 0.f;
    float t3 = have ? __expf(my.w - m3) : 0.f;
    if (small && have) {
        *reinterpret_cast<float4*>(&wex[wid][lane * 4]) = make_float4(t0, t1, t2, t3);
        sE[wid][lane] = sv;
    }
    float u0 = t0, u1 = t1, u2 = t2, u3 = t3;
    if (!small) {
        for (int i = s0 + lane + 64; i < s1; i += 64) {
            float4 lg = lgf4[edge_list[i]];
            u0 += __expf(lg.x - m0); u1 += __expf(lg.y - m1);
            u2 += __expf(lg.z - m2); u3 += __expf(lg.w - m3);
        }
    }
#pragma unroll
    for (int off = 32; off; off >>= 1) {
        u0 += __shfl_xor(u0, off); u1 += __shfl_xor(u1, off);
        u2 += __shfl_xor(u2, off); u3 += __shfl_xor(u3, off);
    }

    // pass 2: lane quarter p -> edges it+p, it+4+p, it+8+p, it+12+p;
    // lane q owns elems 8q..8q+7 (head q>>2)
    int ha = q >> 2;
    float mh = (ha == 0) ? m0 : (ha == 1) ? m1 : (ha == 2) ? m2 : m3;
    float sh = (ha == 0) ? u0 : (ha == 1) ? u1 : (ha == 2) ? u2 : u3;
    float rh = 1.f / sh;
    const unsigned short* FBu = reinterpret_cast<const unsigned short*>(FB);
    float c0 = 0.f, c1 = 0.f, c2 = 0.f, c3 = 0.f, c4 = 0.f, c5 = 0.f, c6 = 0.f, c7 = 0.f;
    if (small) {
        asm volatile("s_waitcnt lgkmcnt(0)" ::: "memory");   // wex/sE visible within wave
        for (int it = 0; it < deg; it += 16) {
            int i0 = it + p, i1 = it + 4 + p, i2 = it + 8 + p, i3 = it + 12 + p;
            bool b0 = i0 < deg, b1 = i1 < deg, b2 = i2 < deg, b3 = i3 < deg;
            int v0 = b0 ? sE[wid][i0] : 0;
            int v1 = b1 ? sE[wid][i1] : 0;
            int v2 = b2 ? sE[wid][i2] : 0;
            int v3 = b3 ? sE[wid][i3] : 0;
            uint4 f0 = b0 ? *reinterpret_cast<const uint4*>(FBu + (size_t)v0 * 128 + q * 8)
                          : make_uint4(0, 0, 0, 0);
            uint4 f1 = b1 ? *reinterpret_cast<const uint4*>(FBu + (size_t)v1 * 128 + q * 8)
                          : make_uint4(0, 0, 0, 0);
            uint4 f2 = b2 ? *reinterpret_cast<const uint4*>(FBu + (size_t)v2 * 128 + q * 8)
                          : make_uint4(0, 0, 0, 0);
            uint4 f3 = b3 ? *reinterpret_cast<const uint4*>(FBu + (size_t)v3 * 128 + q * 8)
                          : make_uint4(0, 0, 0, 0);
            float w0 = b0 ? wex[wid][i0 * 4 + ha] * rh : 0.f;
            float w1 = b1 ? wex[wid][i1 * 4 + ha] * rh : 0.f;
            float w2 = b2 ? wex[wid][i2 * 4 + ha] * rh : 0.f;
            float w3 = b3 ? wex[wid][i3 * 4 + ha] * rh : 0.f;
            c0 += w0 * __uint_as_float(f0.x << 16) + w1 * __uint_as_float(f1.x << 16)
                + w2 * __uint_as_float(f2.x << 16) + w3 * __uint_as_float(f3.x << 16);
            c1 += w0 * __uint_as_float(f0.x & 0xffff0000u) + w1 * __uint_as_float(f1.x & 0xffff0000u)
                + w2 * __uint_as_float(f2.x & 0xffff0000u) + w3 * __uint_as_float(f3.x & 0xffff0000u);
            c2 += w0 * __uint_as_float(f0.y << 16) + w1 * __uint_as_float(f1.y << 16)
                + w2 * __uint_as_float(f2.y << 16) + w3 * __uint_as_float(f3.y << 16);
            c3 += w0 * __uint_as_float(f0.y & 0xffff0000u) + w1 * __uint_as_float(f1.y & 0xffff0000u)
                + w2 * __uint_as_float(f2.y & 0xffff0000u) + w3 * __uint_as_float(f3.y & 0xffff0000u);
            c4 += w0 * __uint_as_float(f0.z << 16) + w1 * __uint_as_float(f1.z << 16)
                + w2 * __uint_as_float(f2.z << 16) + w3 * __uint_as_float(f3.z << 16);
            c5 += w0 * __uint_as_float(f0.z & 0xffff0000u) + w1 * __uint_as_float(f1.z & 0xffff0000u)
                + w2 * __uint_as_float(f2.z & 0xffff0000u) + w3 * __uint_as_float(f3.z & 0xffff0000u);
            c6 += w0 * __uint_as_float(f0.w << 16) + w1 * __uint_as_float(f1.w << 16)
                + w2 * __uint_as_float(f2.w << 16) + w3 * __uint_as_float(f3.w << 16);
            c7 += w0 * __uint_as_float(f0.w & 0xffff0000u) + w1 * __uint_as_float(f1.w & 0xffff0000u)
                + w2 * __uint_as_float(f2.w & 0xffff0000u) + w3 * __uint_as_float(f3.w & 0xffff0000u);
        }
    } else {
        for (int it = s0; it < s1; it += 4) {
            int i = it + p;
            if (i < s1) {
                int ee = edge_list[i];
                int sv2 = srcv[ee];
                float lg = lg4[(size_t)ee * 4 + ha];
                float wgt = __expf(lg - mh) * rh;
                uint4 f = *reinterpret_cast<const uint4*>(FBu + (size_t)sv2 * 128 + q * 8);
                c0 += wgt * __uint_as_float(f.x << 16);
                c1 += wgt * __uint_as_float(f.x & 0xffff0000u);
                c2 += wgt * __uint_as_float(f.y << 16);
                c3 += wgt * __uint_as_float(f.y & 0xffff0000u);
                c4 += wgt * __uint_as_float(f.z << 16);
                c5 += wgt * __uint_as_float(f.z & 0xffff0000u);
                c6 += wgt * __uint_as_float(f.w << 16);
                c7 += wgt * __uint_as_float(f.w & 0xffff0000u);
            }
        }
    }
#pragma unroll
    for (int off = 16; off <= 32; off <<= 1) {
        c0 += __shfl_xor(c0, off); c1 += __shfl_xor(c1, off);
        c2 += __shfl_xor(c2, off); c3 += __shfl_xor(c3, off);
        c4 += __shfl_xor(c4, off); c5 += __shfl_xor(c5, off);
        c6 += __shfl_xor(c6, off); c7 += __shfl_xor(c7, off);
    }
    if (p == 0) {
        o4[2 * q]     = make_float4(c0, c1, c2, c3);
        o4[2 * q + 1] = make_float4(c4, c5, c6, c7);
    }
}

extern "C" void kernel_launch(void* const* d_in, const int* in_sizes, int n_in,
                              void* d_out, int out_size, void* d_ws, size_t ws_size,
                              hipStream_t stream) {
    const float* feats_node = (const float*)d_in[0];
    const float* feats_edge = (const float*)d_in[1];
    const int*   src        = (const int*)d_in[2];
    const int*   dst        = (const int*)d_in[3];
    const float* W          = (const float*)d_in[4];
    const float* al         = (const float*)d_in[5];
    const float* ar         = (const float*)d_in[6];
    const float* ae         = (const float*)d_in[7];
    float* out = (float*)d_out;

    char* ws = (char*)d_ws;
    size_t off = 0;
    __hip_bfloat16* feat_b = (__hip_bfloat16*)(ws + off); off += (size_t)NN * 128 * 2; // 12.8MB
    float* elr    = (float*)(ws + off); off += (size_t)NN * 8 * 4;                      // 1.6MB
    float* vlr    = (float*)(ws + off); off += (size_t)8 * 128 * 4;
    float* logits = (float*)(ws + off); off += (size_t)NE * 4 * 4;                      // 12.8MB
    int* edge_list= (int*)(ws + off);   off += (size_t)NE * 4;                          // 3.2MB
    int* count    = (int*)(ws + off);   off += (size_t)NN * 4;
    int* row_ptr  = (int*)(ws + off);   off += (size_t)(NN + 16) * 4;
    int* cursor   = (int*)(ws + off);   off += (size_t)NN * 4;
    int* bsum     = (int*)(ws + off);   off += (size_t)(SCAN_NB + 16) * 4;
    int* bofs     = (int*)(ws + off);   off += (size_t)(SCAN_NB + 16) * 4;

    hipMemsetAsync(count, 0, (size_t)NN * 4, stream);

    k_prep<<<1, 256, 0, stream>>>(W, al, ar, vlr);
    k_elr<<<ELR_NBLK, 256, 0, stream>>>(feats_node, vlr, elr);
    k_logits_hist<<<(NE + 255) / 256, 256, 0, stream>>>(feats_edge, src, dst, ae, elr,
                                                        (float4*)logits, count);
    k_scan_a<<<SCAN_NB, 256, 0, stream>>>(count, row_ptr, bsum);
    k_scan_b<<<1, 256, 0, stream>>>(bsum, bofs);
    k_scan_c<<<SCAN_NB, 256, 0, stream>>>(row_ptr, bofs, cursor);
    k_proj4<<<PROJ_NBLK, 256, 0, stream>>>(feats_node, W, feat_b);
    k_fill<<<(NE + 255) / 256, 256, 0, stream>>>(dst, cursor, edge_list);
    k_aggr5<<<(NN + 3) / 4, 256, 0, stream>>>(feat_b, logits, src, edge_list, row_ptr, out);
}